// Round 4
// baseline (357.473 us; speedup 1.0000x reference)
//
#include <hip/hip_runtime.h>

typedef unsigned short u16;
typedef unsigned int   u32;
typedef __bf16  bf16x8 __attribute__((ext_vector_type(8)));
typedef float   f32x16 __attribute__((ext_vector_type(16)));

#define CAP      16384
#define L0_ELS   (256*56)                 // W_in^T image: 256 rows x 56 (40 W + bias@40 + pad)
#define HID_ELS  (256*256)
#define OUT_ELS  (32*256)
#define HEAD_WS  (L0_ELS + 3*HID_ELS + OUT_ELS)   // 219136 bf16 elements per head
#define HID_OFF  L0_ELS
#define OUT_OFF  (L0_ELS + 3*HID_ELS)

union F8 { u32 u[4]; bf16x8 v; };

__device__ __forceinline__ u16 f2b(float f) {   // fp32 -> bf16 RTNE
  u32 u = __float_as_uint(f); u += 0x7fffu + ((u >> 16) & 1u); return (u16)(u >> 16);
}
__device__ __forceinline__ u32 packbf2(float a, float b) {  // bf16(a) | bf16(b)<<16
  u32 ua = __float_as_uint(a); ua += 0x7fffu + ((ua >> 16) & 1u);
  u32 ub = __float_as_uint(b); ub += 0x7fffu + ((ub >> 16) & 1u);
  return (ua >> 16) | (ub & 0xffff0000u);
}

__device__ __forceinline__ f32x16 mfma16(bf16x8 a, bf16x8 b, f32x16 c) {
  return __builtin_amdgcn_mfma_f32_32x32x16_bf16(a, b, c, 0, 0, 0);
}

// ---- async staging: global_load_lds width 16 (swizzle pre-baked in global image,
//      so LDS dest is lane-linear: base + tid*16). 256 threads -> 4 KB per sweep. ----
__device__ __forceinline__ void stage_async(const u16* __restrict__ g, short* l,
                                            int bytes, int tid) {
  for (int base = tid * 16; base < bytes; base += 4096)
    __builtin_amdgcn_global_load_lds(
        (const __attribute__((address_space(1))) u32*)((const char*)g + base),
        (__attribute__((address_space(3))) u32*)((char*)l + base), 16, 0, 0);
}

// A-fragment readers (slot-local). i = row-half (0/1) within the 64-row quarter.
__device__ __forceinline__ bf16x8 fragL0(const short* sl, int i, int t, int n, int hh) {
  return *(const bf16x8*)((const char*)sl + (32*i + n)*112 + (2*t + hh)*16);   // 7-chunk rows
}
__device__ __forceinline__ bf16x8 fragH(const short* sl, int i, int t, int n, int hh) {
  return *(const bf16x8*)((const char*)sl + ((32*i + n) << 9) + (((2*t + hh) ^ (n & 7)) << 4)); // XOR-swizzled
}

__device__ __forceinline__ void load_bias_raw(const float* b, int r, int hh, float4 o[4]) {
#pragma unroll
  for (int g = 0; g < 4; ++g) o[g] = *(const float4*)(b + 32*r + 8*g + 4*hh);
}

// D(f32x16, C-layout) -> (+bias) -> relu -> bf16 -> B-layout, SHUFFLE-FREE:
// consuming layers' weight k-columns are permuted (sigma_k in prep) so that
// acc regs 0..7 are exactly this lane's k-slots of tile t0, regs 8..15 of t1.
__device__ __forceinline__ void epilogue(f32x16 c, F8& t0, F8& t1) {
#pragma unroll
  for (int g = 0; g < 4; ++g) {
    t0.u[g] = packbf2(fmaxf(c[2*g],   0.f), fmaxf(c[2*g+1],   0.f));
    t1.u[g] = packbf2(fmaxf(c[8+2*g], 0.f), fmaxf(c[8+2*g+1], 0.f));
  }
}
// hidden-layer variant: bias added before relu (bb0 -> acc elems of t0, bb1 -> t1's source acc)
__device__ __forceinline__ void epilogue_b(f32x16 c, const float4 bb[4], F8& t0, F8& t1) {
  t0.u[0] = packbf2(fmaxf(c[0]  + bb[0].x, 0.f), fmaxf(c[1]  + bb[0].y, 0.f));
  t0.u[1] = packbf2(fmaxf(c[2]  + bb[0].z, 0.f), fmaxf(c[3]  + bb[0].w, 0.f));
  t0.u[2] = packbf2(fmaxf(c[4]  + bb[1].x, 0.f), fmaxf(c[5]  + bb[1].y, 0.f));
  t0.u[3] = packbf2(fmaxf(c[6]  + bb[1].z, 0.f), fmaxf(c[7]  + bb[1].w, 0.f));
  t1.u[0] = packbf2(fmaxf(c[8]  + bb[2].x, 0.f), fmaxf(c[9]  + bb[2].y, 0.f));
  t1.u[1] = packbf2(fmaxf(c[10] + bb[2].z, 0.f), fmaxf(c[11] + bb[2].w, 0.f));
  t1.u[2] = packbf2(fmaxf(c[12] + bb[3].x, 0.f), fmaxf(c[13] + bb[3].y, 0.f));
  t1.u[3] = packbf2(fmaxf(c[14] + bb[3].z, 0.f), fmaxf(c[15] + bb[3].w, 0.f));
}

// image k-position -> source neuron index (inverse of the C-layout->B-layout map).
__device__ __forceinline__ int sigma_k(int k) {
  const int hh  = (k >> 3) & 1;
  const int reg = (k & 7) + 8 * ((k >> 4) & 1);
  return (k & ~31) + (reg & 3) + 8 * (reg >> 2) + 4 * hh;
}

// ---------------- prep: build bf16 W^T images from fp32 inputs ----------------
__global__ void prep(const float* __restrict__ W_in, const float* __restrict__ b_in,
                     const float* __restrict__ W_hid, const float* __restrict__ W_out,
                     u16* __restrict__ ws) {
  const int ct = blockIdx.x * 256 + threadIdx.x;      // 438272 chunks of 8 elements
  const int head = ct / 27392;
  const int r = ct - head * 27392;
  u16 v[8]; int dst;
  if (r < 1792) {                                     // L0: rows n x 56 (k natural: pe input)
    const int nn = r / 7, k0 = (r % 7) * 8;
#pragma unroll
    for (int j = 0; j < 8; ++j) {
      const int k = k0 + j;
      v[j] = (k < 40) ? f2b(W_in[head*10240 + k*256 + nn])
           : (k == 40) ? f2b(b_in[head*256 + nn]) : (u16)0;
    }
    dst = head*HEAD_WS + nn*56 + k0;
  } else if (r < 26368) {                             // hidden: rows n x 256, swizzled, k permuted
    const int q = r - 1792, l = q >> 13, q2 = q & 8191;
    const int nn = q2 >> 5, cc = q2 & 31, kb = 8 * (cc ^ (nn & 7));
#pragma unroll
    for (int j = 0; j < 8; ++j)
      v[j] = f2b(W_hid[head*196608 + l*65536 + sigma_k(kb + j)*256 + nn]);
    dst = head*HEAD_WS + HID_OFF + l*65536 + nn*256 + cc*8;
  } else {                                            // out: 32 rows x 256 (rows>=3 zero), k permuted
    const int q = r - 26368;
    const int nn = q >> 5, cc = q & 31, kb = 8 * (cc ^ (nn & 7));
#pragma unroll
    for (int j = 0; j < 8; ++j)
      v[j] = (nn < 3) ? f2b(W_out[head*768 + sigma_k(kb + j)*3 + nn]) : (u16)0;
    dst = head*HEAD_WS + OUT_OFF + nn*256 + cc*8;
  }
  uint4 o;
  o.x = (u32)v[0] | ((u32)v[1] << 16); o.y = (u32)v[2] | ((u32)v[3] << 16);
  o.z = (u32)v[4] | ((u32)v[5] << 16); o.w = (u32)v[6] | ((u32)v[7] << 16);
  *(uint4*)(ws + dst) = o;
}

__global__ void copy_coords(const uint4* __restrict__ s, uint4* __restrict__ d) {
  const int i = blockIdx.x * 256 + threadIdx.x;
  d[i] = s[i];
}

// ---------------- main fused MLP ----------------
// 256 threads (4 waves) x 128 points; 2 blocks/CU.
// Register budget is the cliff (256/wave at this occupancy): bias is loaded
// per-round and added in the epilogue (no persistent double-buffer), and
// sched_barrier(0) fences pin acc liveness to die at the epilogue.
__launch_bounds__(256, 2)
__global__ void mlp_main(const float* __restrict__ coords, const int* __restrict__ head_idx,
                         const float* __restrict__ b_hid, const float* __restrict__ b_out,
                         const u16* __restrict__ ws, float* __restrict__ out) {
  __shared__ short ring[2 * 16384];                  // 2 x 32 KB weight-quarter slots
  const int tid = threadIdx.x;
  const int lane = tid & 63, wv = tid >> 6;          // wv 0..3
  const int n = lane & 31, hh = lane >> 5;
  const int head = blockIdx.x & 15, chunk = blockIdx.x >> 4;   // head%16 -> fixed XCD (L2 locality)
  const u16* wsh = ws + head * HEAD_WS;

  // stage L0 quarters 0,1 into slots 0,1 (async; drained by barrier below)
  stage_async(wsh + 0*3584, ring,          7168, tid);
  stage_async(wsh + 1*3584, ring + 16384,  7168, tid);

  // gather + positional encoding (B-layout: lane = point, k = 16t + 8*hh + j)
  const int pt = chunk*128 + wv*32 + n;
  const int g  = head_idx[head*CAP + pt];
  const float2 cxy = *(const float2*)(coords + 2*g);
  const float xs = cxy.x, ys = cxy.y;
  const float bo0 = b_out[head*3+0], bo1 = b_out[head*3+1], bo2 = b_out[head*3+2];

  F8 pe[3];
#pragma unroll
  for (int t = 0; t < 3; ++t) {
    float e[8];
#pragma unroll
    for (int half = 0; half < 2; ++half) {
      const int l = 4*t + 2*hh + half;               // k = 4l + comp; comp: sinx,siny,cosx,cosy
      if (l < 10) {
        const float fr = 3.14159265358979323846f * (float)(1 << l);
        float s1, c1, s2, c2;
        sincosf(xs * fr, &s1, &c1);
        sincosf(ys * fr, &s2, &c2);
        e[4*half+0] = s1; e[4*half+1] = s2; e[4*half+2] = c1; e[4*half+3] = c2;
      } else {                                        // k=40 -> 1.0 (folded bias), rest pad 0
        e[4*half+0] = (l == 10) ? 1.0f : 0.0f;
        e[4*half+1] = 0.f; e[4*half+2] = 0.f; e[4*half+3] = 0.f;
      }
    }
    pe[t].u[0] = packbf2(e[0], e[1]); pe[t].u[1] = packbf2(e[2], e[3]);
    pe[t].u[2] = packbf2(e[4], e[5]); pe[t].u[3] = packbf2(e[6], e[7]);
  }

  F8 act0[16], act1[16];
  __syncthreads();                                   // L0 q0/q1 staged

  // ===== layer 0: pe -> act0 (K=48, bias folded into weights) =====
#pragma unroll
  for (int rp = 0; rp < 4; ++rp) {
    short* sl = ring + (rp & 1) * 16384;
    f32x16 acc0 = (f32x16)0.f, acc1 = (f32x16)0.f;
#pragma unroll
    for (int t = 0; t < 3; ++t) {
      acc0 = mfma16(fragL0(sl, 0, t, n, hh), pe[t].v, acc0);
      acc1 = mfma16(fragL0(sl, 1, t, n, hh), pe[t].v, acc1);
    }
    __builtin_amdgcn_sched_barrier(0);
    __syncthreads();                                 // all waves done reading this slot
    const u16* src = (rp < 2) ? (wsh + (rp + 2)*3584) : (wsh + HID_OFF + (rp - 2)*16384);
    const int bytes = (rp < 2) ? 7168 : 32768;
    stage_async(src, sl, bytes, tid);                // fire-and-forget; drained at next barrier
    epilogue(acc0, act0[4*rp+0], act0[4*rp+1]);
    epilogue(acc1, act0[4*rp+2], act0[4*rp+3]);
    __builtin_amdgcn_sched_barrier(0);               // accs die here; no cross-round liveness
  }

  // ===== hidden layers =====
  auto hid_layer = [&](const float* bias, F8 (&ain)[16], F8 (&aout)[16],
                       const u16* j0, const u16* j1, const u16* j2, const u16* j3,
                       int b2, int b3) {
    const u16* jsrc[4] = { j0, j1, j2, j3 };
    const int  jb[4]   = { 32768, 32768, b2, b3 };
#pragma unroll
    for (int rp = 0; rp < 4; ++rp) {
      short* sl = ring + (rp & 1) * 16384;
      // this round's bias: issued early (L2-resident), consumed in epilogue, dies there
      float4 br0[4], br1[4];
      load_bias_raw(bias, 2*rp+0, hh, br0);
      load_bias_raw(bias, 2*rp+1, hh, br1);
      f32x16 acc0 = (f32x16)0.f;
      f32x16 acc1 = (f32x16)0.f;
#pragma unroll
      for (int t = 0; t < 16; ++t) {
        bf16x8 a0 = fragH(sl, 0, t, n, hh);
        bf16x8 a1 = fragH(sl, 1, t, n, hh);
        acc0 = mfma16(a0, ain[t].v, acc0);
        acc1 = mfma16(a1, ain[t].v, acc1);
      }
      __builtin_amdgcn_sched_barrier(0);
      __syncthreads();                                // all waves done with this quarter
      if (jb[rp] > 0) stage_async(jsrc[rp], sl, jb[rp], tid);  // refill freed slot
      epilogue_b(acc0, br0, aout[4*rp+0], aout[4*rp+1]);
      epilogue_b(acc1, br1, aout[4*rp+2], aout[4*rp+3]);
      __builtin_amdgcn_sched_barrier(0);             // accs/bias die here
    }
  };

  const u16* hb = wsh + HID_OFF;
  hid_layer(b_hid + (head*3+0)*256, act0, act1,
            hb + 2*16384, hb + 3*16384, hb + HID_ELS, hb + HID_ELS + 16384, 32768, 32768);
  hid_layer(b_hid + (head*3+1)*256, act1, act0,
            hb + HID_ELS + 2*16384, hb + HID_ELS + 3*16384,
            hb + 2*HID_ELS, hb + 2*HID_ELS + 16384, 32768, 32768);
  hid_layer(b_hid + (head*3+2)*256, act0, act1,
            hb + 2*HID_ELS + 2*16384, hb + 2*HID_ELS + 3*16384,
            wsh + OUT_OFF, (const u16*)0, 16384, 0);

  // ===== out layer: act1 x W_out^T (32-row image in slot 0), scatter =====
  f32x16 acc = (f32x16)0.f;
#pragma unroll
  for (int t = 0; t < 16; ++t)
    acc = mfma16(fragH(ring, 0, t, n, hh), act1[t].v, acc);
  if (hh == 0) {                                     // rows 0..2 live in h=0 regs 0..2
    const long base = (long)g * 3;
    out[base + 0] = acc[0] + bo0;
    out[base + 1] = acc[1] + bo1;
    out[base + 2] = acc[2] + bo2;
  }
}

extern "C" void kernel_launch(void* const* d_in, const int* in_sizes, int n_in,
                              void* d_out, int out_size, void* d_ws, size_t ws_size,
                              hipStream_t stream) {
  const float* coords   = (const float*)d_in[0];
  const int*   head_idx = (const int*)d_in[1];
  const float* W_in     = (const float*)d_in[2];
  const float* b_in     = (const float*)d_in[3];
  const float* W_hid    = (const float*)d_in[4];
  const float* b_hid    = (const float*)d_in[5];
  const float* W_out    = (const float*)d_in[6];
  const float* b_out    = (const float*)d_in[7];
  float* out = (float*)d_out;
  u16*   ws  = (u16*)d_ws;
  if (ws_size < (size_t)HEAD_WS * 16 * sizeof(u16)) return;  // need ~7 MB scratch

  prep<<<dim3(1712), dim3(256), 0, stream>>>(W_in, b_in, W_hid, W_out, ws);
  // second output: coords passthrough (524288 floats = 131072 uint4)
  copy_coords<<<dim3(512), dim3(256), 0, stream>>>((const uint4*)coords, (uint4*)(out + 786432));
  mlp_main<<<dim3(2048), dim3(256), 0, stream>>>(coords, head_idx, b_hid, b_out, ws, out);
}

// Round 5
// 218.409 us; speedup vs baseline: 1.6367x; 1.6367x over previous
//
#include <hip/hip_runtime.h>

typedef unsigned short u16;
typedef unsigned int   u32;
typedef __bf16  bf16x8 __attribute__((ext_vector_type(8)));
typedef float   f32x16 __attribute__((ext_vector_type(16)));

#define CAP      16384
#define L0_ELS   (256*56)                 // W_in^T image: 256 rows x 56 (40 W + bias@40 + pad)
#define HID_ELS  (256*256)
#define OUT_ELS  (32*256)
#define HEAD_WS  (L0_ELS + 3*HID_ELS + OUT_ELS)   // 219136 bf16 elements per head
#define HID_OFF  L0_ELS
#define OUT_OFF  (L0_ELS + 3*HID_ELS)

union F8 { u32 u[4]; bf16x8 v; };

__device__ __forceinline__ u16 f2b(float f) {   // fp32 -> bf16 RTNE
  u32 u = __float_as_uint(f); u += 0x7fffu + ((u >> 16) & 1u); return (u16)(u >> 16);
}
__device__ __forceinline__ u32 packbf2(float a, float b) {  // bf16(a) | bf16(b)<<16
  u32 ua = __float_as_uint(a); ua += 0x7fffu + ((ua >> 16) & 1u);
  u32 ub = __float_as_uint(b); ub += 0x7fffu + ((ub >> 16) & 1u);
  return (ua >> 16) | (ub & 0xffff0000u);
}

__device__ __forceinline__ f32x16 mfma16(bf16x8 a, bf16x8 b, f32x16 c) {
  return __builtin_amdgcn_mfma_f32_32x32x16_bf16(a, b, c, 0, 0, 0);
}

// ---- async staging: global_load_lds width 16 (swizzle pre-baked in global image,
//      so LDS dest is lane-linear: base + tid*16). 256 threads -> 4 KB per sweep. ----
__device__ __forceinline__ void stage_async(const u16* __restrict__ g, short* l,
                                            int bytes, int tid) {
  for (int base = tid * 16; base < bytes; base += 4096)
    __builtin_amdgcn_global_load_lds(
        (const __attribute__((address_space(1))) u32*)((const char*)g + base),
        (__attribute__((address_space(3))) u32*)((char*)l + base), 16, 0, 0);
}

// A-fragment readers (slot-local). i = row-half (0/1) within the 64-row quarter.
__device__ __forceinline__ bf16x8 fragL0(const short* sl, int i, int t, int n, int hh) {
  return *(const bf16x8*)((const char*)sl + (32*i + n)*112 + (2*t + hh)*16);   // 7-chunk rows
}
__device__ __forceinline__ bf16x8 fragH(const short* sl, int i, int t, int n, int hh) {
  return *(const bf16x8*)((const char*)sl + ((32*i + n) << 9) + (((2*t + hh) ^ (n & 7)) << 4)); // XOR-swizzled
}

__device__ __forceinline__ void load_bias_raw(const float* b, int r, int hh, float4 o[4]) {
#pragma unroll
  for (int g = 0; g < 4; ++g) o[g] = *(const float4*)(b + 32*r + 8*g + 4*hh);
}
__device__ __forceinline__ f32x16 bias_to_acc(const float4 raw[4]) {
  f32x16 a;
#pragma unroll
  for (int g = 0; g < 4; ++g) {
    a[4*g+0] = raw[g].x; a[4*g+1] = raw[g].y;
    a[4*g+2] = raw[g].z; a[4*g+3] = raw[g].w;
  }
  return a;
}

// D(f32x16, C-layout) -> relu -> bf16 -> B-layout tiles 2r,2r+1 via lane^32 exchange
__device__ __forceinline__ void epilogue(f32x16 c, int hh, F8& t0, F8& t1) {
  u32 P[8];
#pragma unroll
  for (int i = 0; i < 8; ++i)
    P[i] = packbf2(fmaxf(c[2*i], 0.f), fmaxf(c[2*i+1], 0.f));
  u32 s0 = hh ? P[0] : P[2], s1 = hh ? P[1] : P[3];
  u32 s2 = hh ? P[4] : P[6], s3 = hh ? P[5] : P[7];
  u32 x0 = __shfl_xor(s0, 32, 64), x1 = __shfl_xor(s1, 32, 64);
  u32 x2 = __shfl_xor(s2, 32, 64), x3 = __shfl_xor(s3, 32, 64);
  t0.u[0] = hh ? x0 : P[0]; t0.u[1] = hh ? x1 : P[1];
  t0.u[2] = hh ? P[2] : x0; t0.u[3] = hh ? P[3] : x1;
  t1.u[0] = hh ? x2 : P[4]; t1.u[1] = hh ? x3 : P[5];
  t1.u[2] = hh ? P[6] : x2; t1.u[3] = hh ? P[7] : x3;
}

// ---------------- prep: build bf16 W^T images from fp32 inputs ----------------
// blocks [0,1712): weight-image build; blocks [1712,2224): coords passthrough copy.
__global__ void prep(const float* __restrict__ W_in, const float* __restrict__ b_in,
                     const float* __restrict__ W_hid, const float* __restrict__ W_out,
                     u16* __restrict__ ws,
                     const uint4* __restrict__ csrc, uint4* __restrict__ cdst) {
  if (blockIdx.x >= 1712) {                           // fused copy_coords (saves a launch)
    const int i = (blockIdx.x - 1712) * 256 + threadIdx.x;
    cdst[i] = csrc[i];
    return;
  }
  const int ct = blockIdx.x * 256 + threadIdx.x;      // 438272 chunks of 8 elements
  const int head = ct / 27392;
  const int r = ct - head * 27392;
  u16 v[8]; int dst;
  if (r < 1792) {                                     // L0: rows n x 56
    const int nn = r / 7, k0 = (r % 7) * 8;
#pragma unroll
    for (int j = 0; j < 8; ++j) {
      const int k = k0 + j;
      v[j] = (k < 40) ? f2b(W_in[head*10240 + k*256 + nn])
           : (k == 40) ? f2b(b_in[head*256 + nn]) : (u16)0;
    }
    dst = head*HEAD_WS + nn*56 + k0;
  } else if (r < 26368) {                             // hidden: rows n x 256, swizzled
    const int q = r - 1792, l = q >> 13, q2 = q & 8191;
    const int nn = q2 >> 5, cc = q2 & 31, kb = 8 * (cc ^ (nn & 7));
#pragma unroll
    for (int j = 0; j < 8; ++j)
      v[j] = f2b(W_hid[head*196608 + l*65536 + (kb + j)*256 + nn]);
    dst = head*HEAD_WS + HID_OFF + l*65536 + nn*256 + cc*8;
  } else {                                            // out: 32 rows x 256 (rows>=3 zero)
    const int q = r - 26368;
    const int nn = q >> 5, cc = q & 31, kb = 8 * (cc ^ (nn & 7));
#pragma unroll
    for (int j = 0; j < 8; ++j)
      v[j] = (nn < 3) ? f2b(W_out[head*768 + (kb + j)*3 + nn]) : (u16)0;
    dst = head*HEAD_WS + OUT_OFF + nn*256 + cc*8;
  }
  uint4 o;
  o.x = (u32)v[0] | ((u32)v[1] << 16); o.y = (u32)v[2] | ((u32)v[3] << 16);
  o.z = (u32)v[4] | ((u32)v[5] << 16); o.w = (u32)v[6] | ((u32)v[7] << 16);
  *(uint4*)(ws + dst) = o;
}

// ---------------- main fused MLP ----------------
// 256 threads (4 waves) x 128 points; 2 blocks/CU. Byte-exact R1 structure
// (proven no-spill allocation) + register-neutral s_setprio around MFMA clusters.
__launch_bounds__(256, 2)
__global__ void mlp_main(const float* __restrict__ coords, const int* __restrict__ head_idx,
                         const float* __restrict__ b_hid, const float* __restrict__ b_out,
                         const u16* __restrict__ ws, float* __restrict__ out) {
  __shared__ short ring[2 * 16384];                  // 2 x 32 KB weight-quarter slots
  const int tid = threadIdx.x;
  const int lane = tid & 63, wv = tid >> 6;          // wv 0..3
  const int n = lane & 31, hh = lane >> 5;
  const int head = blockIdx.x & 15, chunk = blockIdx.x >> 4;   // head%16 -> fixed XCD (L2 locality)
  const u16* wsh = ws + head * HEAD_WS;

  // stage L0 quarters 0,1 into slots 0,1 (async; drained by barrier below)
  stage_async(wsh + 0*3584, ring,          7168, tid);
  stage_async(wsh + 1*3584, ring + 16384,  7168, tid);

  // gather + positional encoding (B-layout: lane = point, k = 16t + 8*hh + j)
  const int pt = chunk*128 + wv*32 + n;
  const int g  = head_idx[head*CAP + pt];
  const float2 cxy = *(const float2*)(coords + 2*g);
  const float xs = cxy.x, ys = cxy.y;
  const float bo0 = b_out[head*3+0], bo1 = b_out[head*3+1], bo2 = b_out[head*3+2];

  F8 pe[3];
#pragma unroll
  for (int t = 0; t < 3; ++t) {
    float e[8];
#pragma unroll
    for (int half = 0; half < 2; ++half) {
      const int l = 4*t + 2*hh + half;               // k = 4l + comp; comp: sinx,siny,cosx,cosy
      if (l < 10) {
        const float fr = 3.14159265358979323846f * (float)(1 << l);
        float s1, c1, s2, c2;
        sincosf(xs * fr, &s1, &c1);
        sincosf(ys * fr, &s2, &c2);
        e[4*half+0] = s1; e[4*half+1] = s2; e[4*half+2] = c1; e[4*half+3] = c2;
      } else {                                        // k=40 -> 1.0 (folded bias), rest pad 0
        e[4*half+0] = (l == 10) ? 1.0f : 0.0f;
        e[4*half+1] = 0.f; e[4*half+2] = 0.f; e[4*half+3] = 0.f;
      }
    }
    pe[t].u[0] = packbf2(e[0], e[1]); pe[t].u[1] = packbf2(e[2], e[3]);
    pe[t].u[2] = packbf2(e[4], e[5]); pe[t].u[3] = packbf2(e[6], e[7]);
  }

  F8 act0[16], act1[16];
  __syncthreads();                                   // L0 q0/q1 staged

  // ===== layer 0: pe -> act0 (K=48, bias folded) =====
#pragma unroll
  for (int rp = 0; rp < 4; ++rp) {
    short* sl = ring + (rp & 1) * 16384;
    f32x16 acc0 = (f32x16)0.f, acc1 = (f32x16)0.f;
    __builtin_amdgcn_s_setprio(1);
#pragma unroll
    for (int t = 0; t < 3; ++t) {
      acc0 = mfma16(fragL0(sl, 0, t, n, hh), pe[t].v, acc0);
      acc1 = mfma16(fragL0(sl, 1, t, n, hh), pe[t].v, acc1);
    }
    __builtin_amdgcn_s_setprio(0);
    __syncthreads();                                 // all waves done reading this slot
    const u16* src = (rp < 2) ? (wsh + (rp + 2)*3584) : (wsh + HID_OFF + (rp - 2)*16384);
    const int bytes = (rp < 2) ? 7168 : 32768;
    stage_async(src, sl, bytes, tid);                // fire-and-forget; drained at next barrier
    epilogue(acc0, hh, act0[4*rp+0], act0[4*rp+1]);
    epilogue(acc1, hh, act0[4*rp+2], act0[4*rp+3]);
  }

  // ===== hidden layers =====
  auto hid_layer = [&](const float* bias, F8 (&ain)[16], F8 (&aout)[16],
                       const u16* j0, const u16* j1, const u16* j2, const u16* j3,
                       int b2, int b3) {
    float4 bc0[4], bc1[4], bn0[4], bn1[4];
    load_bias_raw(bias, 0, hh, bc0); load_bias_raw(bias, 1, hh, bc1);
    const u16* jsrc[4] = { j0, j1, j2, j3 };
    const int  jb[4]   = { 32768, 32768, b2, b3 };
#pragma unroll
    for (int rp = 0; rp < 4; ++rp) {
      short* sl = ring + (rp & 1) * 16384;
      if (rp < 3) { load_bias_raw(bias, 2*rp+2, hh, bn0); load_bias_raw(bias, 2*rp+3, hh, bn1); }
      f32x16 acc0 = bias_to_acc(bc0);
      f32x16 acc1 = bias_to_acc(bc1);
      __builtin_amdgcn_s_setprio(1);
#pragma unroll
      for (int t = 0; t < 16; ++t) {
        bf16x8 a0 = fragH(sl, 0, t, n, hh);
        bf16x8 a1 = fragH(sl, 1, t, n, hh);
        acc0 = mfma16(a0, ain[t].v, acc0);
        acc1 = mfma16(a1, ain[t].v, acc1);
      }
      __builtin_amdgcn_s_setprio(0);
      __syncthreads();                                // all waves done with this quarter
      if (jb[rp] > 0) stage_async(jsrc[rp], sl, jb[rp], tid);  // refill freed slot
      epilogue(acc0, hh, aout[4*rp+0], aout[4*rp+1]);
      epilogue(acc1, hh, aout[4*rp+2], aout[4*rp+3]);
      if (rp < 3) {
#pragma unroll
        for (int q = 0; q < 4; ++q) { bc0[q] = bn0[q]; bc1[q] = bn1[q]; }
      }
    }
  };

  const u16* hb = wsh + HID_OFF;
  hid_layer(b_hid + (head*3+0)*256, act0, act1,
            hb + 2*16384, hb + 3*16384, hb + HID_ELS, hb + HID_ELS + 16384, 32768, 32768);
  hid_layer(b_hid + (head*3+1)*256, act1, act0,
            hb + HID_ELS + 2*16384, hb + HID_ELS + 3*16384,
            hb + 2*HID_ELS, hb + 2*HID_ELS + 16384, 32768, 32768);
  hid_layer(b_hid + (head*3+2)*256, act0, act1,
            hb + 2*HID_ELS + 2*16384, hb + 2*HID_ELS + 3*16384,
            wsh + OUT_OFF, (const u16*)0, 16384, 0);

  // ===== out layer: act1 x W_out^T (32-row image in slot 0), scatter =====
  f32x16 acc = (f32x16)0.f;
  __builtin_amdgcn_s_setprio(1);
#pragma unroll
  for (int t = 0; t < 16; ++t)
    acc = mfma16(fragH(ring, 0, t, n, hh), act1[t].v, acc);
  __builtin_amdgcn_s_setprio(0);
  if (hh == 0) {                                     // rows 0..2 live in h=0 regs 0..2
    const long base = (long)g * 3;
    out[base + 0] = acc[0] + bo0;
    out[base + 1] = acc[1] + bo1;
    out[base + 2] = acc[2] + bo2;
  }
}

extern "C" void kernel_launch(void* const* d_in, const int* in_sizes, int n_in,
                              void* d_out, int out_size, void* d_ws, size_t ws_size,
                              hipStream_t stream) {
  const float* coords   = (const float*)d_in[0];
  const int*   head_idx = (const int*)d_in[1];
  const float* W_in     = (const float*)d_in[2];
  const float* b_in     = (const float*)d_in[3];
  const float* W_hid    = (const float*)d_in[4];
  const float* b_hid    = (const float*)d_in[5];
  const float* W_out    = (const float*)d_in[6];
  const float* b_out    = (const float*)d_in[7];
  float* out = (float*)d_out;
  u16*   ws  = (u16*)d_ws;
  if (ws_size < (size_t)HEAD_WS * 16 * sizeof(u16)) return;  // need ~7 MB scratch

  // prep blocks [0,1712) + fused coords passthrough blocks [1712,2224)
  prep<<<dim3(2224), dim3(256), 0, stream>>>(W_in, b_in, W_hid, W_out, ws,
                                             (const uint4*)coords, (uint4*)(out + 786432));
  mlp_main<<<dim3(2048), dim3(256), 0, stream>>>(coords, head_idx, b_hid, b_out, ws, out);
}

// Round 6
// 208.429 us; speedup vs baseline: 1.7151x; 1.0479x over previous
//
#include <hip/hip_runtime.h>

typedef unsigned short u16;
typedef unsigned int   u32;
typedef __bf16  bf16x8 __attribute__((ext_vector_type(8)));
typedef float   f32x16 __attribute__((ext_vector_type(16)));

#define CAP      16384
// Fragment-linear weight images: each 64-row quarter is stored as a sequence of
// fragments; fragment f = 64 contiguous 16B lane-chunks (1024 B). Read addr =
// lane*16 + f*1024 -> canonical conflict-free ds_read_b128, zero addr VALU.
#define L0Q_ELS  3072                     // L0 quarter: 6 frags x 512 els (k=0..47 only)
#define L0_ELS   (4*L0Q_ELS)              // 12288
#define HID_ELS  (256*256)                // 4 quarters x 32 frags x 512
#define OUT_ELS  (16*512)                 // 16 frags (i=0, t=0..15)
#define HEAD_WS  (L0_ELS + 3*HID_ELS + OUT_ELS)   // 217088 bf16 elements per head
#define HID_OFF  L0_ELS
#define OUT_OFF  (L0_ELS + 3*HID_ELS)

union F8 { u32 u[4]; bf16x8 v; };

__device__ __forceinline__ u16 f2b(float f) {   // fp32 -> bf16 RTNE
  u32 u = __float_as_uint(f); u += 0x7fffu + ((u >> 16) & 1u); return (u16)(u >> 16);
}
__device__ __forceinline__ u32 packbf2(float a, float b) {  // bf16(a) | bf16(b)<<16
  u32 ua = __float_as_uint(a); ua += 0x7fffu + ((ua >> 16) & 1u);
  u32 ub = __float_as_uint(b); ub += 0x7fffu + ((ub >> 16) & 1u);
  return (ua >> 16) | (ub & 0xffff0000u);
}

__device__ __forceinline__ f32x16 mfma16(bf16x8 a, bf16x8 b, f32x16 c) {
  return __builtin_amdgcn_mfma_f32_32x32x16_bf16(a, b, c, 0, 0, 0);
}

// ---- async staging: global_load_lds width 16 (image already fragment-linear,
//      LDS dest is lane-linear: base + tid*16). 256 threads -> 4 KB per sweep. ----
__device__ __forceinline__ void stage_async(const u16* __restrict__ g, short* l,
                                            int bytes, int tid) {
  for (int base = tid * 16; base < bytes; base += 4096)
    __builtin_amdgcn_global_load_lds(
        (const __attribute__((address_space(1))) u32*)((const char*)g + base),
        (__attribute__((address_space(3))) u32*)((char*)l + base), 16, 0, 0);
}

// A-fragment readers: fragment-linear, conflict-free, immediate-offset addressing.
// Fragment (i,t) holds rows 32i+n, k-chunk (2t+hh), at lane = hh*32+n.
__device__ __forceinline__ bf16x8 fragL0(const short* sl, int i, int t, int lane) {
  return *(const bf16x8*)((const char*)sl + ((i*3 + t) << 10) + (lane << 4));
}
__device__ __forceinline__ bf16x8 fragH(const short* sl, int i, int t, int lane) {
  return *(const bf16x8*)((const char*)sl + ((i*16 + t) << 10) + (lane << 4));
}

__device__ __forceinline__ void load_bias_raw(const float* b, int r, int hh, float4 o[4]) {
#pragma unroll
  for (int g = 0; g < 4; ++g) o[g] = *(const float4*)(b + 32*r + 8*g + 4*hh);
}
__device__ __forceinline__ f32x16 bias_to_acc(const float4 raw[4]) {
  f32x16 a;
#pragma unroll
  for (int g = 0; g < 4; ++g) {
    a[4*g+0] = raw[g].x; a[4*g+1] = raw[g].y;
    a[4*g+2] = raw[g].z; a[4*g+3] = raw[g].w;
  }
  return a;
}

// D(f32x16, C-layout) -> relu -> bf16 -> B-layout tiles 2r,2r+1 via lane^32 exchange
__device__ __forceinline__ void epilogue(f32x16 c, int hh, F8& t0, F8& t1) {
  u32 P[8];
#pragma unroll
  for (int i = 0; i < 8; ++i)
    P[i] = packbf2(fmaxf(c[2*i], 0.f), fmaxf(c[2*i+1], 0.f));
  u32 s0 = hh ? P[0] : P[2], s1 = hh ? P[1] : P[3];
  u32 s2 = hh ? P[4] : P[6], s3 = hh ? P[5] : P[7];
  u32 x0 = __shfl_xor(s0, 32, 64), x1 = __shfl_xor(s1, 32, 64);
  u32 x2 = __shfl_xor(s2, 32, 64), x3 = __shfl_xor(s3, 32, 64);
  t0.u[0] = hh ? x0 : P[0]; t0.u[1] = hh ? x1 : P[1];
  t0.u[2] = hh ? P[2] : x0; t0.u[3] = hh ? P[3] : x1;
  t1.u[0] = hh ? x2 : P[4]; t1.u[1] = hh ? x3 : P[5];
  t1.u[2] = hh ? P[6] : x2; t1.u[3] = hh ? P[7] : x3;
}

// ---------------- prep: build bf16 fragment-linear W^T images ----------------
// blocks [0,1712): weight-image build; blocks [1712,2224): coords passthrough copy.
__global__ void prep(const float* __restrict__ W_in, const float* __restrict__ b_in,
                     const float* __restrict__ W_hid, const float* __restrict__ W_out,
                     u16* __restrict__ ws,
                     const uint4* __restrict__ csrc, uint4* __restrict__ cdst) {
  if (blockIdx.x >= 1712) {                           // fused copy_coords (saves a launch)
    const int i = (blockIdx.x - 1712) * 256 + threadIdx.x;
    cdst[i] = csrc[i];
    return;
  }
  const int ct = blockIdx.x * 256 + threadIdx.x;      // 438272 chunks of 8 elements
  const int head = ct / 27392;
  const int r = ct - head * 27392;
  u16 v[8]; int dst;
  if (r < 1792) {                                     // L0: 256 rows x 7 chunks (chunk 6 = dead pad)
    const int nn = r / 7, c = r % 7;
    if (c == 6) return;                               // k=48..55 never read
    const int k0 = c * 8;
#pragma unroll
    for (int j = 0; j < 8; ++j) {
      const int k = k0 + j;
      v[j] = (k < 40) ? f2b(W_in[head*10240 + k*256 + nn])
           : (k == 40) ? f2b(b_in[head*256 + nn]) : (u16)0;
    }
    const int Q = nn >> 6, rr = nn & 63, i = rr >> 5, n2 = rr & 31;
    dst = head*HEAD_WS + Q*L0Q_ELS + (((i*3 + (c>>1)) << 6) + ((c&1) << 5) + n2) * 8;
  } else if (r < 26368) {                             // hidden: frag-linear quarters
    const int q = r - 1792, l = q >> 13, q2 = q & 8191;
    const int nn = q2 >> 5, cc = q2 & 31, kb = cc * 8;
#pragma unroll
    for (int j = 0; j < 8; ++j)
      v[j] = f2b(W_hid[head*196608 + l*65536 + (kb + j)*256 + nn]);
    const int Q = nn >> 6, rr = nn & 63, i = rr >> 5, n2 = rr & 31;
    dst = head*HEAD_WS + HID_OFF + l*65536 + Q*16384
        + (((i*16 + (cc>>1)) << 6) + ((cc&1) << 5) + n2) * 8;
  } else {                                            // out: 16 frags (rows>=3 zero)
    const int q = r - 26368;
    const int nn = q >> 5, cc = q & 31, kb = cc * 8;
#pragma unroll
    for (int j = 0; j < 8; ++j)
      v[j] = (nn < 3) ? f2b(W_out[head*768 + (kb + j)*3 + nn]) : (u16)0;
    dst = head*HEAD_WS + OUT_OFF + (((cc>>1) << 6) + ((cc&1) << 5) + nn) * 8;
  }
  uint4 o;
  o.x = (u32)v[0] | ((u32)v[1] << 16); o.y = (u32)v[2] | ((u32)v[3] << 16);
  o.z = (u32)v[4] | ((u32)v[5] << 16); o.w = (u32)v[6] | ((u32)v[7] << 16);
  *(uint4*)(ws + dst) = o;
}

// ---------------- main fused MLP ----------------
// 256 threads (4 waves) x 128 points; 2 blocks/CU. R5 structure (proven
// no-spill allocation + setprio) with fragment-linear conflict-free LDS reads.
__launch_bounds__(256, 2)
__global__ void mlp_main(const float* __restrict__ coords, const int* __restrict__ head_idx,
                         const float* __restrict__ b_hid, const float* __restrict__ b_out,
                         const u16* __restrict__ ws, float* __restrict__ out) {
  __shared__ short ring[2 * 16384];                  // 2 x 32 KB weight-quarter slots
  const int tid = threadIdx.x;
  const int lane = tid & 63, wv = tid >> 6;          // wv 0..3
  const int n = lane & 31, hh = lane >> 5;
  const int head = blockIdx.x & 15, chunk = blockIdx.x >> 4;   // head%16 -> fixed XCD (L2 locality)
  const u16* wsh = ws + head * HEAD_WS;

  // stage L0 quarters 0,1 into slots 0,1 (async; drained by barrier below)
  stage_async(wsh + 0*L0Q_ELS, ring,          6144, tid);
  stage_async(wsh + 1*L0Q_ELS, ring + 16384,  6144, tid);

  // gather + positional encoding (B-layout: lane = point, k = 16t + 8*hh + j)
  const int pt = chunk*128 + wv*32 + n;
  const int g  = head_idx[head*CAP + pt];
  const float2 cxy = *(const float2*)(coords + 2*g);
  const float xs = cxy.x, ys = cxy.y;
  const float bo0 = b_out[head*3+0], bo1 = b_out[head*3+1], bo2 = b_out[head*3+2];

  F8 pe[3];
#pragma unroll
  for (int t = 0; t < 3; ++t) {
    float e[8];
#pragma unroll
    for (int half = 0; half < 2; ++half) {
      const int l = 4*t + 2*hh + half;               // k = 4l + comp; comp: sinx,siny,cosx,cosy
      if (l < 10) {
        const float fr = 3.14159265358979323846f * (float)(1 << l);
        float s1, c1, s2, c2;
        sincosf(xs * fr, &s1, &c1);
        sincosf(ys * fr, &s2, &c2);
        e[4*half+0] = s1; e[4*half+1] = s2; e[4*half+2] = c1; e[4*half+3] = c2;
      } else {                                        // k=40 -> 1.0 (folded bias), rest pad 0
        e[4*half+0] = (l == 10) ? 1.0f : 0.0f;
        e[4*half+1] = 0.f; e[4*half+2] = 0.f; e[4*half+3] = 0.f;
      }
    }
    pe[t].u[0] = packbf2(e[0], e[1]); pe[t].u[1] = packbf2(e[2], e[3]);
    pe[t].u[2] = packbf2(e[4], e[5]); pe[t].u[3] = packbf2(e[6], e[7]);
  }

  F8 act0[16], act1[16];
  __syncthreads();                                   // L0 q0/q1 staged

  // ===== layer 0: pe -> act0 (K=48, bias folded) =====
#pragma unroll
  for (int rp = 0; rp < 4; ++rp) {
    short* sl = ring + (rp & 1) * 16384;
    f32x16 acc0 = (f32x16)0.f, acc1 = (f32x16)0.f;
    __builtin_amdgcn_s_setprio(1);
#pragma unroll
    for (int t = 0; t < 3; ++t) {
      acc0 = mfma16(fragL0(sl, 0, t, lane), pe[t].v, acc0);
      acc1 = mfma16(fragL0(sl, 1, t, lane), pe[t].v, acc1);
    }
    __builtin_amdgcn_s_setprio(0);
    __syncthreads();                                 // all waves done reading this slot
    const u16* src = (rp < 2) ? (wsh + (rp + 2)*L0Q_ELS) : (wsh + HID_OFF + (rp - 2)*16384);
    const int bytes = (rp < 2) ? 6144 : 32768;
    stage_async(src, sl, bytes, tid);                // fire-and-forget; drained at next barrier
    epilogue(acc0, hh, act0[4*rp+0], act0[4*rp+1]);
    epilogue(acc1, hh, act0[4*rp+2], act0[4*rp+3]);
  }

  // ===== hidden layers =====
  auto hid_layer = [&](const float* bias, F8 (&ain)[16], F8 (&aout)[16],
                       const u16* j0, const u16* j1, const u16* j2, const u16* j3,
                       int b2, int b3) {
    float4 bc0[4], bc1[4], bn0[4], bn1[4];
    load_bias_raw(bias, 0, hh, bc0); load_bias_raw(bias, 1, hh, bc1);
    const u16* jsrc[4] = { j0, j1, j2, j3 };
    const int  jb[4]   = { 32768, 32768, b2, b3 };
#pragma unroll
    for (int rp = 0; rp < 4; ++rp) {
      short* sl = ring + (rp & 1) * 16384;
      if (rp < 3) { load_bias_raw(bias, 2*rp+2, hh, bn0); load_bias_raw(bias, 2*rp+3, hh, bn1); }
      f32x16 acc0 = bias_to_acc(bc0);
      f32x16 acc1 = bias_to_acc(bc1);
      __builtin_amdgcn_s_setprio(1);
#pragma unroll
      for (int t = 0; t < 16; ++t) {
        bf16x8 a0 = fragH(sl, 0, t, lane);
        bf16x8 a1 = fragH(sl, 1, t, lane);
        acc0 = mfma16(a0, ain[t].v, acc0);
        acc1 = mfma16(a1, ain[t].v, acc1);
      }
      __builtin_amdgcn_s_setprio(0);
      __syncthreads();                                // all waves done with this quarter
      if (jb[rp] > 0) stage_async(jsrc[rp], sl, jb[rp], tid);  // refill freed slot
      epilogue(acc0, hh, aout[4*rp+0], aout[4*rp+1]);
      epilogue(acc1, hh, aout[4*rp+2], aout[4*rp+3]);
      if (rp < 3) {
#pragma unroll
        for (int q = 0; q < 4; ++q) { bc0[q] = bn0[q]; bc1[q] = bn1[q]; }
      }
    }
  };

  const u16* hb = wsh + HID_OFF;
  hid_layer(b_hid + (head*3+0)*256, act0, act1,
            hb + 2*16384, hb + 3*16384, hb + HID_ELS, hb + HID_ELS + 16384, 32768, 32768);
  hid_layer(b_hid + (head*3+1)*256, act1, act0,
            hb + HID_ELS + 2*16384, hb + HID_ELS + 3*16384,
            hb + 2*HID_ELS, hb + 2*HID_ELS + 16384, 32768, 32768);
  hid_layer(b_hid + (head*3+2)*256, act0, act1,
            hb + 2*HID_ELS + 2*16384, hb + 2*HID_ELS + 3*16384,
            wsh + OUT_OFF, (const u16*)0, 16384, 0);

  // ===== out layer: act1 x W_out^T (16-frag image in slot 0), scatter =====
  f32x16 acc = (f32x16)0.f;
  __builtin_amdgcn_s_setprio(1);
#pragma unroll
  for (int t = 0; t < 16; ++t)
    acc = mfma16(fragH(ring, 0, t, lane), act1[t].v, acc);
  __builtin_amdgcn_s_setprio(0);
  if (hh == 0) {                                     // rows 0..2 live in h=0 regs 0..2
    const long base = (long)g * 3;
    out[base + 0] = acc[0] + bo0;
    out[base + 1] = acc[1] + bo1;
    out[base + 2] = acc[2] + bo2;
  }
}

extern "C" void kernel_launch(void* const* d_in, const int* in_sizes, int n_in,
                              void* d_out, int out_size, void* d_ws, size_t ws_size,
                              hipStream_t stream) {
  const float* coords   = (const float*)d_in[0];
  const int*   head_idx = (const int*)d_in[1];
  const float* W_in     = (const float*)d_in[2];
  const float* b_in     = (const float*)d_in[3];
  const float* W_hid    = (const float*)d_in[4];
  const float* b_hid    = (const float*)d_in[5];
  const float* W_out    = (const float*)d_in[6];
  const float* b_out    = (const float*)d_in[7];
  float* out = (float*)d_out;
  u16*   ws  = (u16*)d_ws;
  if (ws_size < (size_t)HEAD_WS * 16 * sizeof(u16)) return;  // need ~6.9 MB scratch

  // prep blocks [0,1712) + fused coords passthrough blocks [1712,2224)
  prep<<<dim3(2224), dim3(256), 0, stream>>>(W_in, b_in, W_hid, W_out, ws,
                                             (const uint4*)coords, (uint4*)(out + 786432));
  mlp_main<<<dim3(2048), dim3(256), 0, stream>>>(coords, head_idx, b_hid, b_out, ws, out);
}

// Round 7
// 202.461 us; speedup vs baseline: 1.7656x; 1.0295x over previous
//
#include <hip/hip_runtime.h>

typedef unsigned short u16;
typedef unsigned int   u32;
typedef __bf16  bf16x8 __attribute__((ext_vector_type(8)));
typedef float   f32x16 __attribute__((ext_vector_type(16)));

#define CAP      16384
// Fragment-linear weight images: each 64-row quarter is stored as a sequence of
// fragments; fragment f = 64 contiguous 16B lane-chunks (1024 B). Read addr =
// lane*16 + f*1024 -> canonical conflict-free ds_read_b128, zero addr VALU.
#define L0Q_ELS  3072                     // L0 quarter: 6 frags x 512 els (k=0..47 only)
#define L0_ELS   (4*L0Q_ELS)              // 12288
#define HID_ELS  (256*256)                // 4 quarters x 32 frags x 512
#define OUT_ELS  (16*512)                 // 16 frags (i=0, t=0..15)
#define HEAD_WS  (L0_ELS + 3*HID_ELS + OUT_ELS)   // 217088 bf16 elements per head
#define HID_OFF  L0_ELS
#define OUT_OFF  (L0_ELS + 3*HID_ELS)

union F8 { u32 u[4]; bf16x8 v; };

__device__ __forceinline__ u16 f2b(float f) {   // fp32 -> bf16 RTNE
  u32 u = __float_as_uint(f); u += 0x7fffu + ((u >> 16) & 1u); return (u16)(u >> 16);
}
__device__ __forceinline__ u32 packbf2(float a, float b) {  // bf16(a) | bf16(b)<<16
  u32 ua = __float_as_uint(a); ua += 0x7fffu + ((ua >> 16) & 1u);
  u32 ub = __float_as_uint(b); ub += 0x7fffu + ((ub >> 16) & 1u);
  return (ua >> 16) | (ub & 0xffff0000u);
}

__device__ __forceinline__ f32x16 mfma16(bf16x8 a, bf16x8 b, f32x16 c) {
  return __builtin_amdgcn_mfma_f32_32x32x16_bf16(a, b, c, 0, 0, 0);
}

// ---- async staging: global_load_lds width 16 (image already fragment-linear,
//      LDS dest is lane-linear: base + tid*16). 256 threads -> 4 KB per sweep. ----
__device__ __forceinline__ void stage_async(const u16* __restrict__ g, short* l,
                                            int bytes, int tid) {
  for (int base = tid * 16; base < bytes; base += 4096)
    __builtin_amdgcn_global_load_lds(
        (const __attribute__((address_space(1))) u32*)((const char*)g + base),
        (__attribute__((address_space(3))) u32*)((char*)l + base), 16, 0, 0);
}

// A-fragment readers: fragment-linear, conflict-free, immediate-offset addressing.
// Fragment (i,t) holds rows 32i+n, k-chunk (2t+hh), at lane = hh*32+n.
__device__ __forceinline__ bf16x8 fragL0(const short* sl, int i, int t, int lane) {
  return *(const bf16x8*)((const char*)sl + ((i*3 + t) << 10) + (lane << 4));
}
__device__ __forceinline__ bf16x8 fragH(const short* sl, int i, int t, int lane) {
  return *(const bf16x8*)((const char*)sl + ((i*16 + t) << 10) + (lane << 4));
}

__device__ __forceinline__ void load_bias_raw(const float* b, int r, int hh, float4 o[4]) {
#pragma unroll
  for (int g = 0; g < 4; ++g) o[g] = *(const float4*)(b + 32*r + 8*g + 4*hh);
}
__device__ __forceinline__ f32x16 bias_to_acc(const float4 raw[4]) {
  f32x16 a;
#pragma unroll
  for (int g = 0; g < 4; ++g) {
    a[4*g+0] = raw[g].x; a[4*g+1] = raw[g].y;
    a[4*g+2] = raw[g].z; a[4*g+3] = raw[g].w;
  }
  return a;
}

// D(f32x16, C-layout) -> relu -> bf16 -> B-layout tiles 2r,2r+1 via lane^32 exchange
__device__ __forceinline__ void epilogue(f32x16 c, int hh, F8& t0, F8& t1) {
  u32 P[8];
#pragma unroll
  for (int i = 0; i < 8; ++i)
    P[i] = packbf2(fmaxf(c[2*i], 0.f), fmaxf(c[2*i+1], 0.f));
  u32 s0 = hh ? P[0] : P[2], s1 = hh ? P[1] : P[3];
  u32 s2 = hh ? P[4] : P[6], s3 = hh ? P[5] : P[7];
  u32 x0 = __shfl_xor(s0, 32, 64), x1 = __shfl_xor(s1, 32, 64);
  u32 x2 = __shfl_xor(s2, 32, 64), x3 = __shfl_xor(s3, 32, 64);
  t0.u[0] = hh ? x0 : P[0]; t0.u[1] = hh ? x1 : P[1];
  t0.u[2] = hh ? P[2] : x0; t0.u[3] = hh ? P[3] : x1;
  t1.u[0] = hh ? x2 : P[4]; t1.u[1] = hh ? x3 : P[5];
  t1.u[2] = hh ? P[6] : x2; t1.u[3] = hh ? P[7] : x3;
}

// ---------------- prep: LDS-tiled transpose -> fragment-linear bf16 images ----------------
// b <192: hidden quarters (head,l,Q). 192..255: L0 quarters (head,Q).
// 256..271: out images (head). >=272: coords passthrough (512 blocks).
// All global reads (float4 rows, contiguous in n) and all global writes
// (contiguous uint4 chunk streams) are fully coalesced.
__global__ void prep(const float* __restrict__ W_in, const float* __restrict__ b_in,
                     const float* __restrict__ W_hid, const float* __restrict__ W_out,
                     u16* __restrict__ ws,
                     const uint4* __restrict__ csrc, uint4* __restrict__ cdst) {
  const int b = blockIdx.x, tid = threadIdx.x;
  if (b >= 272) {                                   // coords passthrough
    const int i = (b - 272) * 256 + tid;
    cdst[i] = csrc[i];
    return;
  }
  __shared__ u16 lt[256 * 66];                      // bf16 [k][n] tile, pad 66 (33.8 KB)
  if (b < 192) {                                    // hidden quarter: 256 k x 64 neurons
    const int head = b & 15, g = b >> 4, l = g >> 2, Q = g & 3;
    const float* src = W_hid + head*196608 + l*65536 + Q*64;
    const int kr = tid >> 4, q = tid & 15;
#pragma unroll
    for (int s = 0; s < 16; ++s) {
      const int k = s*16 + kr;
      const float4 v = *(const float4*)(src + k*256 + q*4);
      u16* p = lt + k*66 + q*4;
      p[0] = f2b(v.x); p[1] = f2b(v.y); p[2] = f2b(v.z); p[3] = f2b(v.w);
    }
    __syncthreads();
    u16* dq = ws + head*HEAD_WS + HID_OFF + l*65536 + Q*16384;
#pragma unroll
    for (int s = 0; s < 8; ++s) {                   // 2048 lane-chunks of 16 B
      const int ch = s*256 + tid;
      const int f = ch >> 6, ll = ch & 63;
      const int i = f >> 4, t = f & 15, hh = ll >> 5, n2 = ll & 31;
      const int kb = 8*(2*t + hh), rr = i*32 + n2;
      u32 w[4];
#pragma unroll
      for (int d = 0; d < 4; ++d)
        w[d] = (u32)lt[(kb + 2*d)*66 + rr] | ((u32)lt[(kb + 2*d + 1)*66 + rr] << 16);
      uint4 o; o.x = w[0]; o.y = w[1]; o.z = w[2]; o.w = w[3];
      *(uint4*)(dq + ch*8) = o;
    }
  } else if (b < 256) {                             // L0 quarter: 48 k x 64 neurons (+bias row 40)
    const int bb = b - 192, head = bb & 15, Q = bb >> 4;
#pragma unroll
    for (int s = 0; s < 3; ++s) {
      const int idx = s*256 + tid;                  // 768 float4 tiles (48 rows x 16 quads)
      const int k = idx >> 4, q = idx & 15;
      float4 v;
      if (k < 40)       v = *(const float4*)(W_in + head*10240 + k*256 + Q*64 + q*4);
      else if (k == 40) v = *(const float4*)(b_in + head*256 + Q*64 + q*4);
      else { v.x = 0.f; v.y = 0.f; v.z = 0.f; v.w = 0.f; }
      u16* p = lt + k*66 + q*4;
      p[0] = f2b(v.x); p[1] = f2b(v.y); p[2] = f2b(v.z); p[3] = f2b(v.w);
    }
    __syncthreads();
    u16* dq = ws + head*HEAD_WS + Q*L0Q_ELS;
#pragma unroll
    for (int s = 0; s < 2; ++s) {                   // 384 lane-chunks
      const int ch = s*256 + tid;
      if (ch < 384) {
        const int f = ch >> 6, ll = ch & 63;
        const int i = (f >= 3) ? 1 : 0, t = f - 3*i, hh = ll >> 5, n2 = ll & 31;
        const int kb = 8*(2*t + hh), rr = i*32 + n2;
        u32 w[4];
#pragma unroll
        for (int d = 0; d < 4; ++d)
          w[d] = (u32)lt[(kb + 2*d)*66 + rr] | ((u32)lt[(kb + 2*d + 1)*66 + rr] << 16);
        uint4 o; o.x = w[0]; o.y = w[1]; o.z = w[2]; o.w = w[3];
        *(uint4*)(dq + ch*8) = o;
      }
    }
  } else {                                          // out image: 16 frags, rows>=3 zero
    const int head = b - 256;
#pragma unroll
    for (int s = 0; s < 3; ++s) {
      const int idx = s*256 + tid;                  // 768 floats
      lt[idx] = f2b(W_out[head*768 + idx]);
    }
    __syncthreads();
    u16* dq = ws + head*HEAD_WS + OUT_OFF;
#pragma unroll
    for (int s = 0; s < 4; ++s) {                   // 1024 lane-chunks
      const int ch = s*256 + tid;
      const int t = ch >> 6, ll = ch & 63;
      const int hh = ll >> 5, n2 = ll & 31;
      const int kb = 8*(2*t + hh);
      u32 w[4] = {0u, 0u, 0u, 0u};
      if (n2 < 3) {
#pragma unroll
        for (int d = 0; d < 4; ++d)
          w[d] = (u32)lt[(kb + 2*d)*3 + n2] | ((u32)lt[(kb + 2*d + 1)*3 + n2] << 16);
      }
      uint4 o; o.x = w[0]; o.y = w[1]; o.z = w[2]; o.w = w[3];
      *(uint4*)(dq + ch*8) = o;
    }
  }
}

// ---------------- main fused MLP ----------------
// 256 threads (4 waves) x 128 points; 2 blocks/CU. R6 structure UNCHANGED
// (proven no-spill allocation + setprio + fragment-linear conflict-free LDS).
__launch_bounds__(256, 2)
__global__ void mlp_main(const float* __restrict__ coords, const int* __restrict__ head_idx,
                         const float* __restrict__ b_hid, const float* __restrict__ b_out,
                         const u16* __restrict__ ws, float* __restrict__ out) {
  __shared__ short ring[2 * 16384];                  // 2 x 32 KB weight-quarter slots
  const int tid = threadIdx.x;
  const int lane = tid & 63, wv = tid >> 6;          // wv 0..3
  const int n = lane & 31, hh = lane >> 5;
  const int head = blockIdx.x & 15, chunk = blockIdx.x >> 4;   // head%16 -> fixed XCD (L2 locality)
  const u16* wsh = ws + head * HEAD_WS;

  // stage L0 quarters 0,1 into slots 0,1 (async; drained by barrier below)
  stage_async(wsh + 0*L0Q_ELS, ring,          6144, tid);
  stage_async(wsh + 1*L0Q_ELS, ring + 16384,  6144, tid);

  // gather + positional encoding (B-layout: lane = point, k = 16t + 8*hh + j)
  const int pt = chunk*128 + wv*32 + n;
  const int g  = head_idx[head*CAP + pt];
  const float2 cxy = *(const float2*)(coords + 2*g);
  const float xs = cxy.x, ys = cxy.y;
  const float bo0 = b_out[head*3+0], bo1 = b_out[head*3+1], bo2 = b_out[head*3+2];

  F8 pe[3];
#pragma unroll
  for (int t = 0; t < 3; ++t) {
    float e[8];
#pragma unroll
    for (int half = 0; half < 2; ++half) {
      const int l = 4*t + 2*hh + half;               // k = 4l + comp; comp: sinx,siny,cosx,cosy
      if (l < 10) {
        const float fr = 3.14159265358979323846f * (float)(1 << l);
        float s1, c1, s2, c2;
        sincosf(xs * fr, &s1, &c1);
        sincosf(ys * fr, &s2, &c2);
        e[4*half+0] = s1; e[4*half+1] = s2; e[4*half+2] = c1; e[4*half+3] = c2;
      } else {                                        // k=40 -> 1.0 (folded bias), rest pad 0
        e[4*half+0] = (l == 10) ? 1.0f : 0.0f;
        e[4*half+1] = 0.f; e[4*half+2] = 0.f; e[4*half+3] = 0.f;
      }
    }
    pe[t].u[0] = packbf2(e[0], e[1]); pe[t].u[1] = packbf2(e[2], e[3]);
    pe[t].u[2] = packbf2(e[4], e[5]); pe[t].u[3] = packbf2(e[6], e[7]);
  }

  F8 act0[16], act1[16];
  __syncthreads();                                   // L0 q0/q1 staged

  // ===== layer 0: pe -> act0 (K=48, bias folded) =====
#pragma unroll
  for (int rp = 0; rp < 4; ++rp) {
    short* sl = ring + (rp & 1) * 16384;
    f32x16 acc0 = (f32x16)0.f, acc1 = (f32x16)0.f;
    __builtin_amdgcn_s_setprio(1);
#pragma unroll
    for (int t = 0; t < 3; ++t) {
      acc0 = mfma16(fragL0(sl, 0, t, lane), pe[t].v, acc0);
      acc1 = mfma16(fragL0(sl, 1, t, lane), pe[t].v, acc1);
    }
    __builtin_amdgcn_s_setprio(0);
    __syncthreads();                                 // all waves done reading this slot
    const u16* src = (rp < 2) ? (wsh + (rp + 2)*L0Q_ELS) : (wsh + HID_OFF + (rp - 2)*16384);
    const int bytes = (rp < 2) ? 6144 : 32768;
    stage_async(src, sl, bytes, tid);                // fire-and-forget; drained at next barrier
    epilogue(acc0, hh, act0[4*rp+0], act0[4*rp+1]);
    epilogue(acc1, hh, act0[4*rp+2], act0[4*rp+3]);
  }

  // ===== hidden layers =====
  auto hid_layer = [&](const float* bias, F8 (&ain)[16], F8 (&aout)[16],
                       const u16* j0, const u16* j1, const u16* j2, const u16* j3,
                       int b2, int b3) {
    float4 bc0[4], bc1[4], bn0[4], bn1[4];
    load_bias_raw(bias, 0, hh, bc0); load_bias_raw(bias, 1, hh, bc1);
    const u16* jsrc[4] = { j0, j1, j2, j3 };
    const int  jb[4]   = { 32768, 32768, b2, b3 };
#pragma unroll
    for (int rp = 0; rp < 4; ++rp) {
      short* sl = ring + (rp & 1) * 16384;
      if (rp < 3) { load_bias_raw(bias, 2*rp+2, hh, bn0); load_bias_raw(bias, 2*rp+3, hh, bn1); }
      f32x16 acc0 = bias_to_acc(bc0);
      f32x16 acc1 = bias_to_acc(bc1);
      __builtin_amdgcn_s_setprio(1);
#pragma unroll
      for (int t = 0; t < 16; ++t) {
        bf16x8 a0 = fragH(sl, 0, t, lane);
        bf16x8 a1 = fragH(sl, 1, t, lane);
        acc0 = mfma16(a0, ain[t].v, acc0);
        acc1 = mfma16(a1, ain[t].v, acc1);
      }
      __builtin_amdgcn_s_setprio(0);
      __syncthreads();                                // all waves done with this quarter
      if (jb[rp] > 0) stage_async(jsrc[rp], sl, jb[rp], tid);  // refill freed slot
      epilogue(acc0, hh, aout[4*rp+0], aout[4*rp+1]);
      epilogue(acc1, hh, aout[4*rp+2], aout[4*rp+3]);
      if (rp < 3) {
#pragma unroll
        for (int q = 0; q < 4; ++q) { bc0[q] = bn0[q]; bc1[q] = bn1[q]; }
      }
    }
  };

  const u16* hb = wsh + HID_OFF;
  hid_layer(b_hid + (head*3+0)*256, act0, act1,
            hb + 2*16384, hb + 3*16384, hb + HID_ELS, hb + HID_ELS + 16384, 32768, 32768);
  hid_layer(b_hid + (head*3+1)*256, act1, act0,
            hb + HID_ELS + 2*16384, hb + HID_ELS + 3*16384,
            hb + 2*HID_ELS, hb + 2*HID_ELS + 16384, 32768, 32768);
  hid_layer(b_hid + (head*3+2)*256, act0, act1,
            hb + 2*HID_ELS + 2*16384, hb + 2*HID_ELS + 3*16384,
            wsh + OUT_OFF, (const u16*)0, 16384, 0);

  // ===== out layer: act1 x W_out^T (16-frag image in slot 0), scatter =====
  f32x16 acc = (f32x16)0.f;
  __builtin_amdgcn_s_setprio(1);
#pragma unroll
  for (int t = 0; t < 16; ++t)
    acc = mfma16(fragH(ring, 0, t, lane), act1[t].v, acc);
  __builtin_amdgcn_s_setprio(0);
  if (hh == 0) {                                     // rows 0..2 live in h=0 regs 0..2
    const long base = (long)g * 3;
    out[base + 0] = acc[0] + bo0;
    out[base + 1] = acc[1] + bo1;
    out[base + 2] = acc[2] + bo2;
  }
}

extern "C" void kernel_launch(void* const* d_in, const int* in_sizes, int n_in,
                              void* d_out, int out_size, void* d_ws, size_t ws_size,
                              hipStream_t stream) {
  const float* coords   = (const float*)d_in[0];
  const int*   head_idx = (const int*)d_in[1];
  const float* W_in     = (const float*)d_in[2];
  const float* b_in     = (const float*)d_in[3];
  const float* W_hid    = (const float*)d_in[4];
  const float* b_hid    = (const float*)d_in[5];
  const float* W_out    = (const float*)d_in[6];
  const float* b_out    = (const float*)d_in[7];
  float* out = (float*)d_out;
  u16*   ws  = (u16*)d_ws;
  if (ws_size < (size_t)HEAD_WS * 16 * sizeof(u16)) return;  // need ~6.9 MB scratch

  // prep: 192 hidden-quarter + 64 L0-quarter + 16 out blocks + 512 coords-copy blocks
  prep<<<dim3(784), dim3(256), 0, stream>>>(W_in, b_in, W_hid, W_out, ws,
                                            (const uint4*)coords, (uint4*)(out + 786432));
  mlp_main<<<dim3(2048), dim3(256), 0, stream>>>(coords, head_idx, b_hid, b_out, ws, out);
}